// Round 1
// baseline (128.900 us; speedup 1.0000x reference)
//
#include <hip/hip_runtime.h>

#define EPSV 1e-8f

// Kernel 1: per-(graph,chunk) block accumulates sum of cos(tdir, gpos[g]-atom)
// over its atoms, for all G=8 global nodes, into acc[b*G+g] via atomics.
__global__ __launch_bounds__(256) void cos_partial_kernel(
    const float* __restrict__ atom_pos,   // [N,3]
    const float* __restrict__ gpos,       // [B*G,3]
    const float* __restrict__ tdir,       // [N,3]
    float* __restrict__ acc,              // [B*G] pre-zeroed
    int n_per_graph, int G, int chunks_per_graph, int atoms_per_chunk)
{
    const int b     = blockIdx.x / chunks_per_graph;
    const int chunk = blockIdx.x % chunks_per_graph;
    const int base  = b * n_per_graph + chunk * atoms_per_chunk;

    // Global-node positions for this graph: 8 x 3 floats in registers
    // (uniform per block -> L2-broadcast reads, trivial cost).
    float gx[8], gy[8], gz[8];
    const float* gp = gpos + (size_t)b * G * 3;
#pragma unroll
    for (int g = 0; g < 8; ++g) {
        gx[g] = gp[g * 3 + 0];
        gy[g] = gp[g * 3 + 1];
        gz[g] = gp[g * 3 + 2];
    }

    float accg[8];
#pragma unroll
    for (int g = 0; g < 8; ++g) accg[g] = 0.0f;

    for (int i = threadIdx.x; i < atoms_per_chunk; i += blockDim.x) {
        const size_t idx = (size_t)(base + i) * 3;
        const float ax = atom_pos[idx + 0];
        const float ay = atom_pos[idx + 1];
        const float az = atom_pos[idx + 2];
        const float tx = tdir[idx + 0];
        const float ty = tdir[idx + 1];
        const float tz = tdir[idx + 2];
        const float tn = sqrtf(tx * tx + ty * ty + tz * tz);
#pragma unroll
        for (int g = 0; g < 8; ++g) {
            const float dx = gx[g] - ax;
            const float dy = gy[g] - ay;
            const float dz = gz[g] - az;
            const float dot = tx * dx + ty * dy + tz * dz;
            const float pn  = sqrtf(dx * dx + dy * dy + dz * dz);
            const float den = fmaxf(tn * pn, EPSV);
            accg[g] += __fdividef(dot, den);
        }
    }

    // 64-lane butterfly reduce per g, then one atomic per wave per g.
    const int lane = threadIdx.x & 63;
#pragma unroll
    for (int g = 0; g < 8; ++g) {
        float v = accg[g];
        for (int off = 32; off > 0; off >>= 1)
            v += __shfl_down(v, off);
        if (lane == 0)
            atomicAdd(&acc[b * G + g], v);
    }
}

// Kernel 2: one wave. Thread b -> per-graph min/argmin; lane-reduce for mean.
__global__ __launch_bounds__(64) void finalize_kernel(
    const float* __restrict__ acc,  // [B*G]
    float* __restrict__ out,        // [1 + B]
    int B, int G, float inv_n)
{
    const int b = threadIdx.x;
    float minloss = 0.0f;
    if (b < B) {
        minloss = 3.402823e+38f;
        int minidx = 0;
        for (int g = 0; g < G; ++g) {
            const float loss = 1.0f - acc[b * G + g] * inv_n;
            if (loss < minloss) {  // strict < : first-occurrence argmin (jnp semantics)
                minloss = loss;
                minidx = g;
            }
        }
        out[1 + b] = (float)minidx;
    }
    float v = (b < B) ? minloss : 0.0f;
    for (int off = 32; off > 0; off >>= 1)
        v += __shfl_down(v, off);
    if (b == 0) out[0] = v / (float)B;
}

extern "C" void kernel_launch(void* const* d_in, const int* in_sizes, int n_in,
                              void* d_out, int out_size, void* d_ws, size_t ws_size,
                              hipStream_t stream) {
    const float* atom_pos = (const float*)d_in[0];
    const float* gpos     = (const float*)d_in[1];
    const float* tdir     = (const float*)d_in[2];
    // batch indices (d_in[3], d_in[4]) unused: uniform batching is guaranteed.
    // num_graphs (d_in[5]) is a device scalar; B is fixed by the problem.
    const int B  = 64;
    const int N  = in_sizes[0] / 3;   // 1048576
    const int Gt = in_sizes[1] / 3;   // 512
    const int n  = N / B;             // 16384
    const int G  = Gt / B;            // 8

    float* acc = (float*)d_ws;        // [B*G] floats
    hipMemsetAsync(acc, 0, (size_t)B * G * sizeof(float), stream);

    const int chunks = 16;            // 64*16 = 1024 blocks -> 4 blocks/CU
    const int apc    = n / chunks;    // 1024 atoms per block
    cos_partial_kernel<<<B * chunks, 256, 0, stream>>>(
        atom_pos, gpos, tdir, acc, n, G, chunks, apc);

    finalize_kernel<<<1, 64, 0, stream>>>(acc, (float*)d_out, B, G,
                                          1.0f / (float)n);
}

// Round 2
// 85.306 us; speedup vs baseline: 1.5110x; 1.5110x over previous
//
#include <hip/hip_runtime.h>

// Problem constants (uniform batching guaranteed by setup_inputs).
constexpr int B_GRAPHS = 64;
constexpr int N_PER_GRAPH = 16384;
constexpr int GPN = 8;                 // global nodes per graph
constexpr int THREADS = 256;
constexpr int ATOMS_PER_THREAD = 4;    // 48 B per array per thread = 3x float4
constexpr int BLOCKS_PER_GRAPH = N_PER_GRAPH / (THREADS * ATOMS_PER_THREAD); // 16
constexpr int NBLOCKS = B_GRAPHS * BLOCKS_PER_GRAPH;  // 1024

// Kernel 1: each thread processes 4 atoms x 8 global nodes.
// cos = dot * rsq(|t|^2) * rsq(|p|^2)  (one v_rsq per pair, no div/sqrt fixups)
// Reduce: 64-lane butterfly per g -> LDS across 4 waves -> partials[block][g].
__global__ __launch_bounds__(THREADS) void cos_partial(
    const float* __restrict__ atom_pos,   // [N,3]
    const float* __restrict__ gpos,       // [B*GPN,3]
    const float* __restrict__ tdir,       // [N,3]
    float* __restrict__ partials)         // [NBLOCKS][GPN]
{
    const int b  = blockIdx.x / BLOCKS_PER_GRAPH;       // graph (uniform)
    const int tg = blockIdx.x * THREADS + threadIdx.x;  // global thread id

    // Issue all 6 dwordx4 loads up-front (independent, coalesced, 16B-aligned).
    const float4* ap4 = (const float4*)atom_pos;
    const float4* td4 = (const float4*)tdir;
    const size_t fb = (size_t)tg * 3;
    const float4 a0 = ap4[fb + 0], a1 = ap4[fb + 1], a2 = ap4[fb + 2];
    const float4 t0 = td4[fb + 0], t1 = td4[fb + 1], t2 = td4[fb + 2];

    // Global-node positions: uniform address per block -> scalar loads.
    float gx[GPN], gy[GPN], gz[GPN];
    const float* gp = gpos + (size_t)b * GPN * 3;
#pragma unroll
    for (int g = 0; g < GPN; ++g) {
        gx[g] = gp[g * 3 + 0];
        gy[g] = gp[g * 3 + 1];
        gz[g] = gp[g * 3 + 2];
    }

    // Unpack 4 atoms / 4 tdirs from the float4s.
    const float ax[4] = {a0.x, a0.w, a1.z, a2.y};
    const float ay[4] = {a0.y, a1.x, a1.w, a2.z};
    const float az[4] = {a0.z, a1.y, a2.x, a2.w};
    const float tx[4] = {t0.x, t0.w, t1.z, t2.y};
    const float ty[4] = {t0.y, t1.x, t1.w, t2.z};
    const float tz[4] = {t0.z, t1.y, t2.x, t2.w};

    float accg[GPN];
#pragma unroll
    for (int g = 0; g < GPN; ++g) accg[g] = 0.0f;

#pragma unroll
    for (int a = 0; a < 4; ++a) {
        const float tn2 = fmaf(tx[a], tx[a], fmaf(ty[a], ty[a], tz[a] * tz[a]));
        const float itn = __builtin_amdgcn_rsqf(fmaxf(tn2, 1e-20f));
#pragma unroll
        for (int g = 0; g < GPN; ++g) {
            const float dx = gx[g] - ax[a];
            const float dy = gy[g] - ay[a];
            const float dz = gz[g] - az[a];
            const float dot = fmaf(tx[a], dx, fmaf(ty[a], dy, tz[a] * dz));
            const float pn2 = fmaf(dx, dx, fmaf(dy, dy, dz * dz));
            const float ipn = __builtin_amdgcn_rsqf(fmaxf(pn2, 1e-20f));
            accg[g] = fmaf(dot * itn, ipn, accg[g]);
        }
    }

    // 64-lane butterfly per g.
    const int lane = threadIdx.x & 63;
    const int wave = threadIdx.x >> 6;
#pragma unroll
    for (int g = 0; g < GPN; ++g) {
        float v = accg[g];
#pragma unroll
        for (int off = 32; off > 0; off >>= 1)
            v += __shfl_xor(v, off);
        accg[g] = v;
    }

    __shared__ float lsum[THREADS / 64][GPN];
    if (lane == 0) {
#pragma unroll
        for (int g = 0; g < GPN; ++g) lsum[wave][g] = accg[g];
    }
    __syncthreads();
    if (threadIdx.x < GPN) {
        const int g = threadIdx.x;
        float s = 0.0f;
#pragma unroll
        for (int w = 0; w < THREADS / 64; ++w) s += lsum[w][g];
        partials[(size_t)blockIdx.x * GPN + g] = s;
    }
}

// Kernel 2: one block of 512 threads. Thread (b,g) sums its 16 chunk partials;
// threads 0..63 then do per-graph argmin + wave-reduce the mean.
__global__ __launch_bounds__(512) void finalize(
    const float* __restrict__ partials,   // [NBLOCKS][GPN] = [B][16][GPN]
    float* __restrict__ out)              // [1 + B]
{
    __shared__ float sums[B_GRAPHS * GPN];
    const int t = threadIdx.x;            // t = b*8 + g
    const int b = t >> 3, g = t & 7;
    float s = 0.0f;
#pragma unroll
    for (int c = 0; c < BLOCKS_PER_GRAPH; ++c)
        s += partials[((size_t)(b * BLOCKS_PER_GRAPH + c)) * GPN + g];
    sums[t] = s;
    __syncthreads();

    if (t < B_GRAPHS) {                   // exactly wave 0
        float minloss = 1e30f;
        int minidx = 0;
#pragma unroll
        for (int g2 = 0; g2 < GPN; ++g2) {
            const float loss = 1.0f - sums[t * GPN + g2] * (1.0f / (float)N_PER_GRAPH);
            if (loss < minloss) {         // strict <: first-occurrence argmin
                minloss = loss;
                minidx = g2;
            }
        }
        out[1 + t] = (float)minidx;
        float v = minloss;
#pragma unroll
        for (int off = 32; off > 0; off >>= 1)
            v += __shfl_down(v, off);
        if (t == 0) out[0] = v * (1.0f / (float)B_GRAPHS);
    }
}

extern "C" void kernel_launch(void* const* d_in, const int* in_sizes, int n_in,
                              void* d_out, int out_size, void* d_ws, size_t ws_size,
                              hipStream_t stream) {
    const float* atom_pos = (const float*)d_in[0];
    const float* gpos     = (const float*)d_in[1];
    const float* tdir     = (const float*)d_in[2];
    // d_in[3], d_in[4] (batch indices) unused: uniform batching.

    float* partials = (float*)d_ws;   // [NBLOCKS][GPN] floats = 32 KiB

    cos_partial<<<NBLOCKS, THREADS, 0, stream>>>(atom_pos, gpos, tdir, partials);
    finalize<<<1, 512, 0, stream>>>(partials, (float*)d_out);
}